// Round 4
// baseline (5651.395 us; speedup 1.0000x reference)
//
#include <hip/hip_runtime.h>

static constexpr int D        = 64;   // N_FACTORS
static constexpr int N_LAYERS = 3;
static constexpr int SH       = 6;    // 64 rows per bucket
static constexpr int RPB      = 1 << SH;

// ===========================================================================
// k_init: emb0 = concat(user_emb, item_emb) -> cur and acc
// ===========================================================================
__global__ void k_init(const float4* __restrict__ ue, const float4* __restrict__ ie,
                       float4* __restrict__ cur, float4* __restrict__ acc,
                       int nUser4, int nTot4) {
    int stride = gridDim.x * blockDim.x;
    for (int i = blockIdx.x * blockDim.x + threadIdx.x; i < nTot4; i += stride) {
        float4 v = (i < nUser4) ? ue[i] : ie[i - nUser4];
        cur[i] = v;
        acc[i] = v;
    }
}

// ===========================================================================
// Bucket partition build. bucket = row >> SH (2344 buckets), 8 XCD groups.
// cnt/cur layout grp-major [g*NB + b] -> XCD-disjoint counter cache lines.
// ecv region of bucket b = [S[8b], S[8(b+1)}) ; edges unsorted within bucket.
// ===========================================================================
__global__ void k_bhist(const int* __restrict__ row, int* __restrict__ cnt,
                        int nnz, int NB) {
    int g = blockIdx.x & 7;
    int stride = gridDim.x * blockDim.x;
    for (int e = blockIdx.x * blockDim.x + threadIdx.x; e < nnz; e += stride)
        atomicAdd(&cnt[g * NB + (row[e] >> SH)], 1);
}

// Single-block exclusive scan over M = NB*8 counts in (bucket-major, grp-minor)
// order; writes S[0..M] (sentinel at M) and initializes cur (grp-major).
__global__ void k_scan(const int* __restrict__ cnt, int* __restrict__ S,
                       int* __restrict__ cur, int NB, int M) {
    __shared__ int tsum[256];
    int tid = threadIdx.x;
    int per = (M + 255) / 256;
    int i0  = tid * per;
    int sum = 0;
    for (int k = 0; k < per; ++k) {
        int i = i0 + k;
        if (i < M) sum += cnt[(i & 7) * NB + (i >> 3)];
    }
    tsum[tid] = sum;
    __syncthreads();
    for (int off = 1; off < 256; off <<= 1) {
        int v = (tid >= off) ? tsum[tid - off] : 0;
        __syncthreads();
        tsum[tid] += v;
        __syncthreads();
    }
    int run = tsum[tid] - sum;
    for (int k = 0; k < per; ++k) {
        int i = i0 + k;
        if (i < M) {
            int b = i >> 3, g = i & 7;
            int c = cnt[g * NB + b];
            S[i] = run;
            cur[g * NB + b] = run;
            run += c;
        }
    }
    if (tid == 255) S[M] = tsum[255];   // == nnz
}

// Partition scatter: ecv[p] = (row_low<<18 | col, val-bits).
__global__ void k_pscatter(const int* __restrict__ row, const int* __restrict__ col,
                           const float* __restrict__ val, int* __restrict__ cur,
                           int2* __restrict__ ecv, int nnz, int NB) {
    int g = blockIdx.x & 7;
    int stride = gridDim.x * blockDim.x;
    for (int e = blockIdx.x * blockDim.x + threadIdx.x; e < nnz; e += stride) {
        int r = row[e];
        int p = atomicAdd(&cur[g * NB + (r >> SH)], 1);
        ecv[p] = make_int2(((r & (RPB - 1)) << 18) | col[e], __float_as_int(val[e]));
    }
}

// ===========================================================================
// SpMM: one block per bucket. 16 KB LDS accumulator (64 rows x 64 f32).
// 16-lane group per edge: float4 gather of a 16B chunk of x[col], LDS-atomic
// add into the local row. Unsorted edges OK. Coalesced float4 epilogue with
// fused running-mean update (acc += y; *0.25 on last layer).
// ===========================================================================
template <bool WRITE_Y, bool LAST>
__global__ __launch_bounds__(256) void k_spmm_lds(const int* __restrict__ S,
                                                  const int2* __restrict__ ecv,
                                                  const float* __restrict__ x,
                                                  float* __restrict__ y,
                                                  float* __restrict__ acc, int N) {
    __shared__ float lacc[RPB * D];      // 16 KB
    int b   = blockIdx.x;
    int tid = threadIdx.x;
    #pragma unroll
    for (int i = tid; i < RPB * D / 4; i += 256)
        ((float4*)lacc)[i] = make_float4(0.f, 0.f, 0.f, 0.f);
    __syncthreads();

    int e0  = S[b * 8];
    int e1  = S[b * 8 + 8];
    int grp = tid >> 4;                  // 16 edge-groups per block
    int ch  = tid & 15;                  // 16B chunk within the 256B row
    int e   = e0 + grp;
    for (; e + 16 < e1; e += 32) {       // unroll 2: two gathers in flight
        int2 a = ecv[e];
        int2 c = ecv[e + 16];
        float4 xa = *(const float4*)(x + ((size_t)(a.x & 0x3FFFF) << 6) + (ch << 2));
        float4 xc = *(const float4*)(x + ((size_t)(c.x & 0x3FFFF) << 6) + (ch << 2));
        float va = __int_as_float(a.y);
        float vc = __int_as_float(c.y);
        int ia = ((unsigned)a.x >> 18) * D + (ch << 2);
        int ic = ((unsigned)c.x >> 18) * D + (ch << 2);
        atomicAdd(&lacc[ia + 0], va * xa.x);
        atomicAdd(&lacc[ia + 1], va * xa.y);
        atomicAdd(&lacc[ia + 2], va * xa.z);
        atomicAdd(&lacc[ia + 3], va * xa.w);
        atomicAdd(&lacc[ic + 0], vc * xc.x);
        atomicAdd(&lacc[ic + 1], vc * xc.y);
        atomicAdd(&lacc[ic + 2], vc * xc.z);
        atomicAdd(&lacc[ic + 3], vc * xc.w);
    }
    if (e < e1) {
        int2 a = ecv[e];
        float4 xa = *(const float4*)(x + ((size_t)(a.x & 0x3FFFF) << 6) + (ch << 2));
        float va = __int_as_float(a.y);
        int ia = ((unsigned)a.x >> 18) * D + (ch << 2);
        atomicAdd(&lacc[ia + 0], va * xa.x);
        atomicAdd(&lacc[ia + 1], va * xa.y);
        atomicAdd(&lacc[ia + 2], va * xa.z);
        atomicAdd(&lacc[ia + 3], va * xa.w);
    }
    __syncthreads();

    int base_row = b << SH;
    #pragma unroll
    for (int i = tid; i < RPB * 16; i += 256) {
        int gr = base_row + (i >> 4);
        if (gr < N) {
            float4 sv = ((const float4*)lacc)[i];
            size_t o = ((size_t)gr << 6) + ((i & 15) << 2);
            if (WRITE_Y) *(float4*)(y + o) = sv;
            float4 av = *(const float4*)(acc + o);
            av.x += sv.x; av.y += sv.y; av.z += sv.z; av.w += sv.w;
            if (LAST) { av.x *= 0.25f; av.y *= 0.25f; av.z *= 0.25f; av.w *= 0.25f; }
            *(float4*)(acc + o) = av;
        }
    }
}

// ===========================================================================
// Fallback (round-1 atomic path) if ws is too small
// ===========================================================================
__global__ void k_spmm_atomic(const int* __restrict__ row, const int* __restrict__ col,
                              const float* __restrict__ val, const float* __restrict__ x,
                              float* __restrict__ y, int nnz) {
    long long total  = (long long)nnz * 16;
    long long stride = (long long)gridDim.x * blockDim.x;
    for (long long idx = (long long)blockIdx.x * blockDim.x + threadIdx.x;
         idx < total; idx += stride) {
        int e = (int)(idx >> 4);
        int c = (int)(idx & 15);
        int r = row[e];
        int ssrc = col[e];
        float v = val[e];
        float4 xv = *(const float4*)(x + (size_t)ssrc * D + c * 4);
        float* yp = y + (size_t)r * D + c * 4;
        atomicAdd(yp + 0, v * xv.x);
        atomicAdd(yp + 1, v * xv.y);
        atomicAdd(yp + 2, v * xv.z);
        atomicAdd(yp + 3, v * xv.w);
    }
}

__global__ void k_acc(const float4* __restrict__ nxt, float4* __restrict__ acc,
                      float scale, int n4) {
    int stride = gridDim.x * blockDim.x;
    for (int i = blockIdx.x * blockDim.x + threadIdx.x; i < n4; i += stride) {
        float4 a = acc[i];
        float4 b = nxt[i];
        a.x = (a.x + b.x) * scale;
        a.y = (a.y + b.y) * scale;
        a.z = (a.z + b.z) * scale;
        a.w = (a.w + b.w) * scale;
        acc[i] = a;
    }
}

// ===========================================================================
extern "C" void kernel_launch(void* const* d_in, const int* in_sizes, int n_in,
                              void* d_out, int out_size, void* d_ws, size_t ws_size,
                              hipStream_t stream) {
    const float* ue  = (const float*)d_in[0];
    const float* ie  = (const float*)d_in[1];
    const int*   row = (const int*)  d_in[2];
    const int*   col = (const int*)  d_in[3];
    const float* val = (const float*)d_in[4];

    const int n_users = in_sizes[0] / D;
    const int n_items = in_sizes[1] / D;
    const int nnz     = in_sizes[2];
    const int N       = n_users + n_items;
    const int NB      = (N + RPB - 1) >> SH;   // 2344
    const int M       = NB * 8;

    float* acc = (float*)d_out;
    const size_t denseB = (size_t)N * D * sizeof(float);
    auto aup = [](size_t x) { return (x + 255) & ~(size_t)255; };

    size_t off = 0;
    float* bufA = (float*)((char*)d_ws + off); off += aup(denseB);
    float* bufB = (float*)((char*)d_ws + off); off += aup(denseB);
    int2*  ecv  = (int2*) ((char*)d_ws + off); off += aup((size_t)nnz * 8);
    int*   cnt  = (int*)  ((char*)d_ws + off); off += aup((size_t)M * 4);
    int*   cur  = (int*)  ((char*)d_ws + off); off += aup((size_t)M * 4);
    int*   S    = (int*)  ((char*)d_ws + off); off += aup((size_t)(M + 1) * 4);
    const size_t needCSR = off;

    const int nTot4  = N * D / 4;
    const int nUser4 = n_users * D / 4;

    if (ws_size >= needCSR) {
        // ---- bucket partition build ----
        hipMemsetAsync(cnt, 0, (size_t)M * 4, stream);
        k_bhist<<<8192, 256, 0, stream>>>(row, cnt, nnz, NB);
        k_scan<<<1, 256, 0, stream>>>(cnt, S, cur, NB, M);
        k_pscatter<<<8192, 256, 0, stream>>>(row, col, val, cur, ecv, nnz, NB);

        // ---- init + 3 fused SpMM layers ----
        k_init<<<2048, 256, 0, stream>>>((const float4*)ue, (const float4*)ie,
                                         (float4*)bufA, (float4*)acc, nUser4, nTot4);
        k_spmm_lds<true,  false><<<NB, 256, 0, stream>>>(S, ecv, bufA, bufB, acc, N);
        k_spmm_lds<true,  false><<<NB, 256, 0, stream>>>(S, ecv, bufB, bufA, acc, N);
        k_spmm_lds<false, true ><<<NB, 256, 0, stream>>>(S, ecv, bufA, bufA, acc, N);
    } else {
        // ---- fallback: atomic scatter path ----
        float* fa = (float*)d_ws;
        float* fb = fa + (size_t)N * D;
        k_init<<<2048, 256, 0, stream>>>((const float4*)ue, (const float4*)ie,
                                         (float4*)fa, (float4*)acc, nUser4, nTot4);
        float* curp = fa;
        float* nxt  = fb;
        for (int l = 0; l < N_LAYERS; ++l) {
            hipMemsetAsync(nxt, 0, denseB, stream);
            k_spmm_atomic<<<8192, 256, 0, stream>>>(row, col, val, curp, nxt, nnz);
            float scale = (l == N_LAYERS - 1) ? (1.0f / (N_LAYERS + 1)) : 1.0f;
            k_acc<<<2048, 256, 0, stream>>>((const float4*)nxt, (float4*)acc, scale, nTot4);
            float* t = curp; curp = nxt; nxt = t;
        }
    }
}

// Round 5
// 837.898 us; speedup vs baseline: 6.7447x; 6.7447x over previous
//
#include <hip/hip_runtime.h>

static constexpr int D        = 64;   // N_FACTORS
static constexpr int N_LAYERS = 3;

// ---------------- bf16 helpers (RNE pack, exact unpack) ----------------
__device__ inline unsigned pack_bf2(float a, float b) {
    unsigned ua = __float_as_uint(a); ua = (ua + 0x7FFFu + ((ua >> 16) & 1u)) >> 16;
    unsigned ub = __float_as_uint(b); ub = (ub + 0x7FFFu + ((ub >> 16) & 1u)) >> 16;
    return ua | (ub << 16);
}
__device__ inline float blo(unsigned u) { return __uint_as_float(u << 16); }
__device__ inline float bhi(unsigned u) { return __uint_as_float(u & 0xFFFF0000u); }

// ===========================================================================
// k_init: acc(fp32) = emb0 ; cur(bf16) = emb0.  i indexes 8-float groups.
// ===========================================================================
__global__ void k_init_bf(const float4* __restrict__ ue, const float4* __restrict__ ie,
                          uint4* __restrict__ cur, float4* __restrict__ acc,
                          int nUser8, int nTot8) {
    int stride = gridDim.x * blockDim.x;
    for (int i = blockIdx.x * blockDim.x + threadIdx.x; i < nTot8; i += stride) {
        float4 f0, f1;
        if (i < nUser8) { f0 = ue[2 * i];              f1 = ue[2 * i + 1]; }
        else            { int j = i - nUser8; f0 = ie[2 * j]; f1 = ie[2 * j + 1]; }
        acc[2 * i]     = f0;
        acc[2 * i + 1] = f1;
        cur[i] = make_uint4(pack_bf2(f0.x, f0.y), pack_bf2(f0.z, f0.w),
                            pack_bf2(f1.x, f1.y), pack_bf2(f1.z, f1.w));
    }
}

// ===========================================================================
// CSR build (round-2 proven path: per-row counting sort)
// ===========================================================================
__global__ void k_hist(const int* __restrict__ row, int* __restrict__ counts, int nnz) {
    int stride = gridDim.x * blockDim.x;
    for (int e = blockIdx.x * blockDim.x + threadIdx.x; e < nnz; e += stride)
        atomicAdd(&counts[row[e]], 1);
}

__global__ void k_scan_block(const int* __restrict__ counts, int* __restrict__ out,
                             int* __restrict__ bsums, int n) {
    __shared__ int s[256];
    int base = blockIdx.x * 1024 + threadIdx.x * 4;
    int c0 = (base + 0 < n) ? counts[base + 0] : 0;
    int c1 = (base + 1 < n) ? counts[base + 1] : 0;
    int c2 = (base + 2 < n) ? counts[base + 2] : 0;
    int c3 = (base + 3 < n) ? counts[base + 3] : 0;
    int tsum = c0 + c1 + c2 + c3;
    s[threadIdx.x] = tsum;
    __syncthreads();
    for (int off = 1; off < 256; off <<= 1) {
        int v = (threadIdx.x >= off) ? s[threadIdx.x - off] : 0;
        __syncthreads();
        s[threadIdx.x] += v;
        __syncthreads();
    }
    int excl = s[threadIdx.x] - tsum;
    if (threadIdx.x == 255) bsums[blockIdx.x] = s[255];
    if (base + 0 < n) out[base + 0] = excl;
    if (base + 1 < n) out[base + 1] = excl + c0;
    if (base + 2 < n) out[base + 2] = excl + c0 + c1;
    if (base + 3 < n) out[base + 3] = excl + c0 + c1 + c2;
}

__global__ void k_scan_sums(int* __restrict__ bsums, int nB) {
    __shared__ int s[256];
    int v = (threadIdx.x < nB) ? bsums[threadIdx.x] : 0;
    s[threadIdx.x] = v;
    __syncthreads();
    for (int off = 1; off < 256; off <<= 1) {
        int u = (threadIdx.x >= off) ? s[threadIdx.x - off] : 0;
        __syncthreads();
        s[threadIdx.x] += u;
        __syncthreads();
    }
    if (threadIdx.x < nB) bsums[threadIdx.x] = s[threadIdx.x] - v;
}

__global__ void k_finalize(int* __restrict__ rowptr, int* __restrict__ cursor,
                           const int* __restrict__ bsums, int n, int nnz) {
    int stride = gridDim.x * blockDim.x;
    for (int i = blockIdx.x * blockDim.x + threadIdx.x; i <= n; i += stride) {
        if (i < n) {
            int v = rowptr[i] + bsums[i >> 10];
            rowptr[i] = v;
            cursor[i] = v;
        } else {
            rowptr[n] = nnz;
        }
    }
}

__global__ void k_scatter(const int* __restrict__ row, const int* __restrict__ col,
                          const float* __restrict__ val, int* __restrict__ cursor,
                          int2* __restrict__ ecv, int nnz) {
    int stride = gridDim.x * blockDim.x;
    for (int e = blockIdx.x * blockDim.x + threadIdx.x; e < nnz; e += stride) {
        int r = row[e];
        int p = atomicAdd(&cursor[r], 1);
        ecv[p] = make_int2(col[e], __float_as_int(val[e]));
    }
}

// ===========================================================================
// SpMM (bf16 x): one wave per row. lane = grp*8 + ch; 8 edge-groups per wave,
// lane gathers 16 B (= 8 bf16) of x[col]. fp32 accumulate, unroll 2.
// shfl_xor(8,16,32) reduce; fused acc(fp32) update; y written bf16.
// ===========================================================================
template <bool WRITE_Y, bool LAST>
__global__ void k_spmm_bf(const int* __restrict__ rowptr, const int2* __restrict__ ecv,
                          const uint4* __restrict__ x, uint4* __restrict__ y,
                          float* __restrict__ acc, int N) {
    int wid = (blockIdx.x * blockDim.x + threadIdx.x) >> 6;
    if (wid >= N) return;
    int lane = threadIdx.x & 63;
    int grp  = lane >> 3;          // edge slot within wave [0,8)
    int ch   = lane & 7;           // 16B chunk of the 128B bf16 row
    int e0 = rowptr[wid];
    int e1 = rowptr[wid + 1];
    float s0 = 0.f, s1 = 0.f, s2 = 0.f, s3 = 0.f;
    float s4 = 0.f, s5 = 0.f, s6 = 0.f, s7 = 0.f;
    int e = e0 + grp;
    for (; e + 8 < e1; e += 16) {
        int2 A = ecv[e];
        int2 C = ecv[e + 8];
        uint4 xa = x[(size_t)A.x * 8 + ch];
        uint4 xc = x[(size_t)C.x * 8 + ch];
        float va = __int_as_float(A.y);
        float vc = __int_as_float(C.y);
        s0 += va * blo(xa.x) + vc * blo(xc.x);
        s1 += va * bhi(xa.x) + vc * bhi(xc.x);
        s2 += va * blo(xa.y) + vc * blo(xc.y);
        s3 += va * bhi(xa.y) + vc * bhi(xc.y);
        s4 += va * blo(xa.z) + vc * blo(xc.z);
        s5 += va * bhi(xa.z) + vc * bhi(xc.z);
        s6 += va * blo(xa.w) + vc * blo(xc.w);
        s7 += va * bhi(xa.w) + vc * bhi(xc.w);
    }
    if (e < e1) {
        int2 A = ecv[e];
        uint4 xa = x[(size_t)A.x * 8 + ch];
        float va = __int_as_float(A.y);
        s0 += va * blo(xa.x); s1 += va * bhi(xa.x);
        s2 += va * blo(xa.y); s3 += va * bhi(xa.y);
        s4 += va * blo(xa.z); s5 += va * bhi(xa.z);
        s6 += va * blo(xa.w); s7 += va * bhi(xa.w);
    }
    // reduce the 8 edge-groups; xor masks 8,16,32 preserve ch = lane&7
    #pragma unroll
    for (int m = 8; m <= 32; m <<= 1) {
        s0 += __shfl_xor(s0, m); s1 += __shfl_xor(s1, m);
        s2 += __shfl_xor(s2, m); s3 += __shfl_xor(s3, m);
        s4 += __shfl_xor(s4, m); s5 += __shfl_xor(s5, m);
        s6 += __shfl_xor(s6, m); s7 += __shfl_xor(s7, m);
    }
    if (grp == 0) {
        if (WRITE_Y)
            y[(size_t)wid * 8 + ch] = make_uint4(pack_bf2(s0, s1), pack_bf2(s2, s3),
                                                 pack_bf2(s4, s5), pack_bf2(s6, s7));
        size_t o = ((size_t)wid << 6) + (ch << 3);
        float4 a0 = *(const float4*)(acc + o);
        float4 a1 = *(const float4*)(acc + o + 4);
        a0.x += s0; a0.y += s1; a0.z += s2; a0.w += s3;
        a1.x += s4; a1.y += s5; a1.z += s6; a1.w += s7;
        if (LAST) {
            a0.x *= 0.25f; a0.y *= 0.25f; a0.z *= 0.25f; a0.w *= 0.25f;
            a1.x *= 0.25f; a1.y *= 0.25f; a1.z *= 0.25f; a1.w *= 0.25f;
        }
        *(float4*)(acc + o)     = a0;
        *(float4*)(acc + o + 4) = a1;
    }
}

// ===========================================================================
// Fallback (round-1 atomic path, fp32) if ws is too small
// ===========================================================================
__global__ void k_init(const float4* __restrict__ ue, const float4* __restrict__ ie,
                       float4* __restrict__ cur, float4* __restrict__ acc,
                       int nUser4, int nTot4) {
    int stride = gridDim.x * blockDim.x;
    for (int i = blockIdx.x * blockDim.x + threadIdx.x; i < nTot4; i += stride) {
        float4 v = (i < nUser4) ? ue[i] : ie[i - nUser4];
        cur[i] = v;
        acc[i] = v;
    }
}

__global__ void k_spmm_atomic(const int* __restrict__ row, const int* __restrict__ col,
                              const float* __restrict__ val, const float* __restrict__ x,
                              float* __restrict__ y, int nnz) {
    long long total  = (long long)nnz * 16;
    long long stride = (long long)gridDim.x * blockDim.x;
    for (long long idx = (long long)blockIdx.x * blockDim.x + threadIdx.x;
         idx < total; idx += stride) {
        int e = (int)(idx >> 4);
        int c = (int)(idx & 15);
        int r = row[e];
        int ssrc = col[e];
        float v = val[e];
        float4 xv = *(const float4*)(x + (size_t)ssrc * D + c * 4);
        float* yp = y + (size_t)r * D + c * 4;
        atomicAdd(yp + 0, v * xv.x);
        atomicAdd(yp + 1, v * xv.y);
        atomicAdd(yp + 2, v * xv.z);
        atomicAdd(yp + 3, v * xv.w);
    }
}

__global__ void k_acc(const float4* __restrict__ nxt, float4* __restrict__ acc,
                      float scale, int n4) {
    int stride = gridDim.x * blockDim.x;
    for (int i = blockIdx.x * blockDim.x + threadIdx.x; i < n4; i += stride) {
        float4 a = acc[i];
        float4 b = nxt[i];
        a.x = (a.x + b.x) * scale;
        a.y = (a.y + b.y) * scale;
        a.z = (a.z + b.z) * scale;
        a.w = (a.w + b.w) * scale;
        acc[i] = a;
    }
}

// ===========================================================================
extern "C" void kernel_launch(void* const* d_in, const int* in_sizes, int n_in,
                              void* d_out, int out_size, void* d_ws, size_t ws_size,
                              hipStream_t stream) {
    const float* ue  = (const float*)d_in[0];
    const float* ie  = (const float*)d_in[1];
    const int*   row = (const int*)  d_in[2];
    const int*   col = (const int*)  d_in[3];
    const float* val = (const float*)d_in[4];

    const int n_users = in_sizes[0] / D;
    const int n_items = in_sizes[1] / D;
    const int nnz     = in_sizes[2];
    const int N       = n_users + n_items;

    float* acc = (float*)d_out;
    const size_t bf16B = (size_t)N * D * 2;     // 19.2 MB per layer buffer
    auto aup = [](size_t x) { return (x + 255) & ~(size_t)255; };

    size_t off = 0;
    uint4* bufA   = (uint4*)((char*)d_ws + off); off += aup(bf16B);
    uint4* bufB   = (uint4*)((char*)d_ws + off); off += aup(bf16B);
    int2*  ecv    = (int2*) ((char*)d_ws + off); off += aup((size_t)nnz * 8);
    int*   rowptr = (int*)  ((char*)d_ws + off); off += aup((size_t)(N + 1) * 4);
    int*   cursor = (int*)  ((char*)d_ws + off); off += aup((size_t)N * 4);
    int*   bsums  = (int*)  ((char*)d_ws + off); off += aup(1024 * 4);
    const size_t needCSR = off;

    if (ws_size >= needCSR) {
        // ---- CSR build (round-2 proven) ----
        hipMemsetAsync(cursor, 0, (size_t)N * 4, stream);
        k_hist<<<(nnz + 255) / 256, 256, 0, stream>>>(row, cursor, nnz);
        int nB = (N + 1023) / 1024;
        k_scan_block<<<nB, 256, 0, stream>>>(cursor, rowptr, bsums, N);
        k_scan_sums<<<1, 256, 0, stream>>>(bsums, nB);
        k_finalize<<<(N + 256) / 256, 256, 0, stream>>>(rowptr, cursor, bsums, N, nnz);
        k_scatter<<<(nnz + 255) / 256, 256, 0, stream>>>(row, col, val, cursor, ecv, nnz);

        // ---- init + 3 fused SpMM layers (bf16 intermediates) ----
        int nTot8  = N * 8;
        int nUser8 = n_users * 8;
        k_init_bf<<<2048, 256, 0, stream>>>((const float4*)ue, (const float4*)ie,
                                            bufA, (float4*)acc, nUser8, nTot8);
        int grid = (N + 3) / 4;   // one wave per row
        k_spmm_bf<true,  false><<<grid, 256, 0, stream>>>(rowptr, ecv, bufA, bufB, acc, N);
        k_spmm_bf<true,  false><<<grid, 256, 0, stream>>>(rowptr, ecv, bufB, bufA, acc, N);
        k_spmm_bf<false, true ><<<grid, 256, 0, stream>>>(rowptr, ecv, bufA, bufA, acc, N);
    } else {
        // ---- fallback: atomic scatter path (fp32) ----
        const size_t denseB = (size_t)N * D * sizeof(float);
        float* fa = (float*)d_ws;
        float* fb = fa + (size_t)N * D;
        const int nTot4  = N * D / 4;
        const int nUser4 = n_users * D / 4;
        k_init<<<2048, 256, 0, stream>>>((const float4*)ue, (const float4*)ie,
                                         (float4*)fa, (float4*)acc, nUser4, nTot4);
        float* curp = fa;
        float* nxt  = fb;
        for (int l = 0; l < N_LAYERS; ++l) {
            hipMemsetAsync(nxt, 0, denseB, stream);
            k_spmm_atomic<<<8192, 256, 0, stream>>>(row, col, val, curp, nxt, nnz);
            float scale = (l == N_LAYERS - 1) ? (1.0f / (N_LAYERS + 1)) : 1.0f;
            k_acc<<<2048, 256, 0, stream>>>((const float4*)nxt, (float4*)acc, scale, nTot4);
            float* t = curp; curp = nxt; nxt = t;
        }
    }
}